// Round 8
// baseline (86.935 us; speedup 1.0000x reference)
//
#include <hip/hip_runtime.h>

// Modulated deformable depthwise conv, B=8 C=128 H=W=64 K=3 PAD=1 STRIDE=1.
// Round 7: same float4-interleaved LDS sampling structure as round 6, but
// restructured for latency hiding: 256-thread blocks (ROWS=4) so a CU holds
// 4 INDEPENDENT barrier domains (vs 2 lock-stepped 512-blocks), CH=16 with
// NIT=4 so the staging prologue amortizes over 4 compute phases, and
// single-buffer LDS (21.9 KB) with T14 split staging (prefetch next channel
// group into regs during compute, ds_write after the barrier).
// Calibrated: __launch_bounds__ arg2 = blocks/CU; VGPR cap = 512/(waves/SIMD).
// (256,4): 16 waves/CU, 128-VGPR cap -> no spill (round 5/6 evidence).

#define BB 8
#define CC 128
#define HH 64
#define WW 64
#define HWs (HH*WW)
#define KKT 9
#define CH 16              // channels per block
#define NCG (CC/CH)        // 8
#define CPI 4              // channels per LDS float4 cell
#define NIT (CH/CPI)       // 4
#define ROWS 4             // output rows per block
#define NHS (HH/ROWS)      // 16
#define WLO 6
#define WR  (ROWS+14)      // 18 staged rows
#define CLO 6
#define WC  76
#define CELLS (WR*WC)      // 1368 float4 cells = 21.9 KB
#define NTHR 256
#define NK  ((CELLS + NTHR - 1)/NTHR)   // 6

__global__ __launch_bounds__(NTHR, 4)
void mdcn_kernel(const float* __restrict__ x,
                 const float* __restrict__ offset,
                 const float* __restrict__ mask,
                 const float* __restrict__ dynw,
                 float* __restrict__ out)
{
    __shared__ float4 lds[CELLS];

    const int blk = blockIdx.x;
    const int hs = blk & (NHS - 1);
    const int cg = (blk >> 4) & (NCG - 1);
    const int b  = blk >> 7;
    const int tid = threadIdx.x;
    const int w = tid & 63;
    const int h0 = hs * ROWS;
    const int h = h0 + (tid >> 6);

    const float* xg = x + (size_t)(b * CC + cg * CH) * HWs;

    // ---- register staging: 4 coalesced per-plane streams, pads zeroed ----
    float4 stg[NK];
    #define STAGE_LOAD(XP)                                                    \
    do {                                                                      \
        const float* xp_ = (XP);                                              \
        _Pragma("unroll")                                                     \
        for (int k = 0; k < NK; ++k) {                                        \
            const int idx = tid + k * NTHR;                                   \
            float4 v = make_float4(0.f, 0.f, 0.f, 0.f);                       \
            if (idx < CELLS) {                                                \
                const int row = idx / WC;                                     \
                const int col = idx - row * WC - CLO;                         \
                const int ar  = h0 - WLO + row;                               \
                if ((unsigned)ar < (unsigned)HH &&                            \
                    (unsigned)col < (unsigned)WW) {                           \
                    const float* pp = xp_ + ar * WW + col;                    \
                    v.x = pp[0 * HWs]; v.y = pp[1 * HWs];                     \
                    v.z = pp[2 * HWs]; v.w = pp[3 * HWs];                     \
                }                                                             \
            }                                                                 \
            stg[k] = v;                                                       \
        }                                                                     \
    } while (0)

    #define STAGE_WRITE()                                                     \
    do {                                                                      \
        _Pragma("unroll")                                                     \
        for (int k = 0; k < NK; ++k) {                                        \
            const int idx = tid + k * NTHR;                                   \
            if (idx < CELLS) lds[idx] = stg[k];                               \
        }                                                                     \
    } while (0)

    // prologue: issue group-0 loads; metadata VALU overlaps load latency
    STAGE_LOAD(xg);

    // ---- per-tap metadata: m, dy, dx + window offset (compact) ----
    float mv[KKT], dyv[KKT], dxv[KKT];
    int   woff[KKT];
    int   badmask = 0;
    const float* offp = offset + (size_t)b * (2 * KKT) * HWs + h * WW + w;
    const float* mskp = mask   + (size_t)b * KKT * HWs       + h * WW + w;
    #pragma unroll
    for (int t = 0; t < KKT; ++t) {
        const float oy = offp[(2 * t)     * HWs];
        const float ox = offp[(2 * t + 1) * HWs];
        const float m  = mskp[t * HWs];
        const float py = (float)(h - 1 + t / 3) + oy;
        const float px = (float)(w - 1 + t % 3) + ox;
        const float fy = floorf(py), fx = floorf(px);
        const int y0 = (int)fy, x0 = (int)fx;
        dyv[t] = py - fy;
        dxv[t] = px - fx;
        const bool inwin = (y0 >= h0 - WLO) && (y0 <= h0 - WLO + WR - 2) &&
                           (x0 >= -CLO)     && (x0 <= -CLO + WC - 2);
        if (!inwin) {
            badmask |= (1 << t);
            woff[t] = 0;
            mv[t] = 0.f;               // zeroes the LDS contribution
        } else {
            woff[t] = (y0 - (h0 - WLO)) * WC + (x0 + CLO);
            mv[t] = m;                 // pads hold zeros -> no corner masks
        }
    }
    const int anybad = __any(badmask != 0);

    STAGE_WRITE();
    __syncthreads();

    const float* wtb  = dynw + (size_t)(b * CC + cg * CH) * KKT;
    float*       outp = out  + (size_t)(b * CC + cg * CH) * HWs + h * WW + w;

    for (int it = 0; it < NIT; ++it) {
        // T14: issue next group's global loads now; write to LDS after barrier
        if (it + 1 < NIT) {
            STAGE_LOAD(xg + (size_t)(it + 1) * CPI * HWs);
        }

        const float* wt = wtb + it * CPI * KKT;
        float s0 = 0.f, s1 = 0.f, s2 = 0.f, s3 = 0.f;

        #pragma unroll
        for (int t = 0; t < KKT; ++t) {
            const float4 c00 = lds[woff[t]];
            const float4 c01 = lds[woff[t] + 1];
            const float4 c10 = lds[woff[t] + WC];
            const float4 c11 = lds[woff[t] + WC + 1];
            const float dy = dyv[t], dx = dxv[t], m = mv[t];
            const float omdy = 1.f - dy, omdx = 1.f - dx;
            const float w00 = omdy * omdx * m, w01 = omdy * dx * m;
            const float w10 = dy * omdx * m,   w11 = dy * dx * m;
            const float v0 = c00.x * w00 + c01.x * w01 + c10.x * w10 + c11.x * w11;
            const float v1 = c00.y * w00 + c01.y * w01 + c10.y * w10 + c11.y * w11;
            const float v2 = c00.z * w00 + c01.z * w01 + c10.z * w10 + c11.z * w11;
            const float v3 = c00.w * w00 + c01.w * w01 + c10.w * w10 + c11.w * w11;
            s0 += v0 * wt[0 * KKT + t];
            s1 += v1 * wt[1 * KKT + t];
            s2 += v2 * wt[2 * KKT + t];
            s3 += v3 * wt[3 * KKT + t];
        }

        // rare corrective path for out-of-window taps (exact reference math)
        if (anybad) {
            #pragma unroll
            for (int t = 0; t < KKT; ++t) {
                if (badmask & (1 << t)) {
                    const float oy = offp[(2 * t)     * HWs];
                    const float ox = offp[(2 * t + 1) * HWs];
                    const float m  = mskp[t * HWs];
                    const float py = (float)(h - 1 + t / 3) + oy;
                    const float px = (float)(w - 1 + t % 3) + ox;
                    const float fy = floorf(py), fx = floorf(px);
                    const float dy = py - fy, dx = px - fx;
                    const int y0 = (int)fy, x0 = (int)fx;
                    const int y1 = y0 + 1,  x1 = x0 + 1;
                    const int cy0 = min(max(y0, 0), HH - 1);
                    const int cy1 = min(max(y1, 0), HH - 1);
                    const int cx0 = min(max(x0, 0), WW - 1);
                    const int cx1 = min(max(x1, 0), WW - 1);
                    const float m00 = ((unsigned)y0 < HH && (unsigned)x0 < WW) ? 1.f : 0.f;
                    const float m01 = ((unsigned)y0 < HH && (unsigned)x1 < WW) ? 1.f : 0.f;
                    const float m10 = ((unsigned)y1 < HH && (unsigned)x0 < WW) ? 1.f : 0.f;
                    const float m11 = ((unsigned)y1 < HH && (unsigned)x1 < WW) ? 1.f : 0.f;
                    const float omdy = 1.f - dy, omdx = 1.f - dx;
                    #pragma unroll
                    for (int c = 0; c < CPI; ++c) {
                        const float* pl = xg + (size_t)(it * CPI + c) * HWs;
                        const float v = pl[cy0 * WW + cx0] * m00 * (omdy * omdx)
                                      + pl[cy0 * WW + cx1] * m01 * (omdy * dx)
                                      + pl[cy1 * WW + cx0] * m10 * (dy * omdx)
                                      + pl[cy1 * WW + cx1] * m11 * (dy * dx);
                        const float add = v * m * wt[c * KKT + t];
                        if      (c == 0) s0 += add;
                        else if (c == 1) s1 += add;
                        else if (c == 2) s2 += add;
                        else             s3 += add;
                    }
                }
            }
        }

        outp[(size_t)(it * CPI + 0) * HWs] = s0;
        outp[(size_t)(it * CPI + 1) * HWs] = s1;
        outp[(size_t)(it * CPI + 2) * HWs] = s2;
        outp[(size_t)(it * CPI + 3) * HWs] = s3;

        if (it + 1 < NIT) {
            __syncthreads();   // all reads of current buffer done
            STAGE_WRITE();     // overwrite with prefetched next group
            __syncthreads();   // next buffer visible
        }
    }
    #undef STAGE_LOAD
    #undef STAGE_WRITE
}

extern "C" void kernel_launch(void* const* d_in, const int* in_sizes, int n_in,
                              void* d_out, int out_size, void* d_ws, size_t ws_size,
                              hipStream_t stream) {
    const float* x      = (const float*)d_in[0];
    const float* offset = (const float*)d_in[1];
    const float* mask   = (const float*)d_in[2];
    const float* dynw   = (const float*)d_in[3];
    float* out = (float*)d_out;

    dim3 grid(BB * NCG * NHS);   // 8 * 8 * 16 = 1024 blocks
    dim3 block(NTHR);
    mdcn_kernel<<<grid, block, 0, stream>>>(x, offset, mask, dynw, out);
}

// Round 9
// 39.775 us; speedup vs baseline: 2.1857x; 2.1857x over previous
//
#include <hip/hip_runtime.h>

// Modulated deformable depthwise conv, B=8 C=128 H=W=64 K=3 PAD=1 STRIDE=1.
// Round 8: round-7 structure, launch-bounds corrected. Calibration across
// 4 data points: hipcc VGPR cap = 256 / arg2, INDEPENDENT of block size
// ((512,6)->40, (512,4)->64, (512,2)->128, (256,4)->64). Our ~90-reg state
// needs arg2<=2. (256,2) -> 128-reg cap, no spill; actual ~110 VGPR gives
// 4 waves/SIMD = 4 independent 256-thread barrier domains per CU (LDS 22KB
// would allow 7), which is the latency-hiding goal of round 7.

#define BB 8
#define CC 128
#define HH 64
#define WW 64
#define HWs (HH*WW)
#define KKT 9
#define CH 16              // channels per block
#define NCG (CC/CH)        // 8
#define CPI 4              // channels per LDS float4 cell
#define NIT (CH/CPI)       // 4
#define ROWS 4             // output rows per block
#define NHS (HH/ROWS)      // 16
#define WLO 6
#define WR  (ROWS+14)      // 18 staged rows
#define CLO 6
#define WC  76
#define CELLS (WR*WC)      // 1368 float4 cells = 21.9 KB
#define NTHR 256
#define NK  ((CELLS + NTHR - 1)/NTHR)   // 6

__global__ __launch_bounds__(NTHR, 2)
void mdcn_kernel(const float* __restrict__ x,
                 const float* __restrict__ offset,
                 const float* __restrict__ mask,
                 const float* __restrict__ dynw,
                 float* __restrict__ out)
{
    __shared__ float4 lds[CELLS];

    const int blk = blockIdx.x;
    const int hs = blk & (NHS - 1);
    const int cg = (blk >> 4) & (NCG - 1);
    const int b  = blk >> 7;
    const int tid = threadIdx.x;
    const int w = tid & 63;
    const int h0 = hs * ROWS;
    const int h = h0 + (tid >> 6);

    const float* xg = x + (size_t)(b * CC + cg * CH) * HWs;

    // ---- register staging: 4 coalesced per-plane streams, pads zeroed ----
    float4 stg[NK];
    #define STAGE_LOAD(XP)                                                    \
    do {                                                                      \
        const float* xp_ = (XP);                                              \
        _Pragma("unroll")                                                     \
        for (int k = 0; k < NK; ++k) {                                        \
            const int idx = tid + k * NTHR;                                   \
            float4 v = make_float4(0.f, 0.f, 0.f, 0.f);                       \
            if (idx < CELLS) {                                                \
                const int row = idx / WC;                                     \
                const int col = idx - row * WC - CLO;                         \
                const int ar  = h0 - WLO + row;                               \
                if ((unsigned)ar < (unsigned)HH &&                            \
                    (unsigned)col < (unsigned)WW) {                           \
                    const float* pp = xp_ + ar * WW + col;                    \
                    v.x = pp[0 * HWs]; v.y = pp[1 * HWs];                     \
                    v.z = pp[2 * HWs]; v.w = pp[3 * HWs];                     \
                }                                                             \
            }                                                                 \
            stg[k] = v;                                                       \
        }                                                                     \
    } while (0)

    #define STAGE_WRITE()                                                     \
    do {                                                                      \
        _Pragma("unroll")                                                     \
        for (int k = 0; k < NK; ++k) {                                        \
            const int idx = tid + k * NTHR;                                   \
            if (idx < CELLS) lds[idx] = stg[k];                               \
        }                                                                     \
    } while (0)

    // prologue: issue group-0 loads; metadata VALU overlaps load latency
    STAGE_LOAD(xg);

    // ---- per-tap metadata: m, dy, dx + window offset (compact) ----
    float mv[KKT], dyv[KKT], dxv[KKT];
    int   woff[KKT];
    int   badmask = 0;
    const float* offp = offset + (size_t)b * (2 * KKT) * HWs + h * WW + w;
    const float* mskp = mask   + (size_t)b * KKT * HWs       + h * WW + w;
    #pragma unroll
    for (int t = 0; t < KKT; ++t) {
        const float oy = offp[(2 * t)     * HWs];
        const float ox = offp[(2 * t + 1) * HWs];
        const float m  = mskp[t * HWs];
        const float py = (float)(h - 1 + t / 3) + oy;
        const float px = (float)(w - 1 + t % 3) + ox;
        const float fy = floorf(py), fx = floorf(px);
        const int y0 = (int)fy, x0 = (int)fx;
        dyv[t] = py - fy;
        dxv[t] = px - fx;
        const bool inwin = (y0 >= h0 - WLO) && (y0 <= h0 - WLO + WR - 2) &&
                           (x0 >= -CLO)     && (x0 <= -CLO + WC - 2);
        if (!inwin) {
            badmask |= (1 << t);
            woff[t] = 0;
            mv[t] = 0.f;               // zeroes the LDS contribution
        } else {
            woff[t] = (y0 - (h0 - WLO)) * WC + (x0 + CLO);
            mv[t] = m;                 // pads hold zeros -> no corner masks
        }
    }
    const int anybad = __any(badmask != 0);

    STAGE_WRITE();
    __syncthreads();

    const float* wtb  = dynw + (size_t)(b * CC + cg * CH) * KKT;
    float*       outp = out  + (size_t)(b * CC + cg * CH) * HWs + h * WW + w;

    for (int it = 0; it < NIT; ++it) {
        // T14: issue next group's global loads now; write to LDS after barrier
        if (it + 1 < NIT) {
            STAGE_LOAD(xg + (size_t)(it + 1) * CPI * HWs);
        }

        const float* wt = wtb + it * CPI * KKT;
        float s0 = 0.f, s1 = 0.f, s2 = 0.f, s3 = 0.f;

        #pragma unroll
        for (int t = 0; t < KKT; ++t) {
            const float4 c00 = lds[woff[t]];
            const float4 c01 = lds[woff[t] + 1];
            const float4 c10 = lds[woff[t] + WC];
            const float4 c11 = lds[woff[t] + WC + 1];
            const float dy = dyv[t], dx = dxv[t], m = mv[t];
            const float omdy = 1.f - dy, omdx = 1.f - dx;
            const float w00 = omdy * omdx * m, w01 = omdy * dx * m;
            const float w10 = dy * omdx * m,   w11 = dy * dx * m;
            const float v0 = c00.x * w00 + c01.x * w01 + c10.x * w10 + c11.x * w11;
            const float v1 = c00.y * w00 + c01.y * w01 + c10.y * w10 + c11.y * w11;
            const float v2 = c00.z * w00 + c01.z * w01 + c10.z * w10 + c11.z * w11;
            const float v3 = c00.w * w00 + c01.w * w01 + c10.w * w10 + c11.w * w11;
            s0 += v0 * wt[0 * KKT + t];
            s1 += v1 * wt[1 * KKT + t];
            s2 += v2 * wt[2 * KKT + t];
            s3 += v3 * wt[3 * KKT + t];
        }

        // rare corrective path for out-of-window taps (exact reference math)
        if (anybad) {
            #pragma unroll
            for (int t = 0; t < KKT; ++t) {
                if (badmask & (1 << t)) {
                    const float oy = offp[(2 * t)     * HWs];
                    const float ox = offp[(2 * t + 1) * HWs];
                    const float m  = mskp[t * HWs];
                    const float py = (float)(h - 1 + t / 3) + oy;
                    const float px = (float)(w - 1 + t % 3) + ox;
                    const float fy = floorf(py), fx = floorf(px);
                    const float dy = py - fy, dx = px - fx;
                    const int y0 = (int)fy, x0 = (int)fx;
                    const int y1 = y0 + 1,  x1 = x0 + 1;
                    const int cy0 = min(max(y0, 0), HH - 1);
                    const int cy1 = min(max(y1, 0), HH - 1);
                    const int cx0 = min(max(x0, 0), WW - 1);
                    const int cx1 = min(max(x1, 0), WW - 1);
                    const float m00 = ((unsigned)y0 < HH && (unsigned)x0 < WW) ? 1.f : 0.f;
                    const float m01 = ((unsigned)y0 < HH && (unsigned)x1 < WW) ? 1.f : 0.f;
                    const float m10 = ((unsigned)y1 < HH && (unsigned)x0 < WW) ? 1.f : 0.f;
                    const float m11 = ((unsigned)y1 < HH && (unsigned)x1 < WW) ? 1.f : 0.f;
                    const float omdy = 1.f - dy, omdx = 1.f - dx;
                    #pragma unroll
                    for (int c = 0; c < CPI; ++c) {
                        const float* pl = xg + (size_t)(it * CPI + c) * HWs;
                        const float v = pl[cy0 * WW + cx0] * m00 * (omdy * omdx)
                                      + pl[cy0 * WW + cx1] * m01 * (omdy * dx)
                                      + pl[cy1 * WW + cx0] * m10 * (dy * omdx)
                                      + pl[cy1 * WW + cx1] * m11 * (dy * dx);
                        const float add = v * m * wt[c * KKT + t];
                        if      (c == 0) s0 += add;
                        else if (c == 1) s1 += add;
                        else if (c == 2) s2 += add;
                        else             s3 += add;
                    }
                }
            }
        }

        outp[(size_t)(it * CPI + 0) * HWs] = s0;
        outp[(size_t)(it * CPI + 1) * HWs] = s1;
        outp[(size_t)(it * CPI + 2) * HWs] = s2;
        outp[(size_t)(it * CPI + 3) * HWs] = s3;

        if (it + 1 < NIT) {
            __syncthreads();   // all reads of current buffer done
            STAGE_WRITE();     // overwrite with prefetched next group
            __syncthreads();   // next buffer visible
        }
    }
    #undef STAGE_LOAD
    #undef STAGE_WRITE
}

extern "C" void kernel_launch(void* const* d_in, const int* in_sizes, int n_in,
                              void* d_out, int out_size, void* d_ws, size_t ws_size,
                              hipStream_t stream) {
    const float* x      = (const float*)d_in[0];
    const float* offset = (const float*)d_in[1];
    const float* mask   = (const float*)d_in[2];
    const float* dynw   = (const float*)d_in[3];
    float* out = (float*)d_out;

    dim3 grid(BB * NCG * NHS);   // 8 * 8 * 16 = 1024 blocks
    dim3 block(NTHR);
    mdcn_kernel<<<grid, block, 0, stream>>>(x, offset, mask, dynw, out);
}

// Round 10
// 39.060 us; speedup vs baseline: 2.2257x; 1.0183x over previous
//
#include <hip/hip_runtime.h>

// Modulated deformable depthwise conv, B=8 C=128 H=W=64 K=3 PAD=1 STRIDE=1.
// Round 9: kill the residual spill. Round 8 had VGPR pinned at the 128 cap
// with ~59 MB scratch writes: stg[6] (24 regs) live across the whole
// compute loop spilled, and STAGE_WRITE then stalled on scratch reloads
// inside the barrier window. Fix: split staging -- H1 (3 float4, 12 regs)
// issued before compute (hidden under it), H2 issued after compute but
// before the barrier (hidden under out-stores + barrier arrival skew).
// Peak live state ~100 regs -> no spill. All else unchanged from round 8.

#define BB 8
#define CC 128
#define HH 64
#define WW 64
#define HWs (HH*WW)
#define KKT 9
#define CH 16              // channels per block
#define NCG (CC/CH)        // 8
#define CPI 4              // channels per LDS float4 cell
#define NIT (CH/CPI)       // 4
#define ROWS 4             // output rows per block
#define NHS (HH/ROWS)      // 16
#define WLO 6
#define WR  (ROWS+14)      // 18 staged rows
#define CLO 6
#define WC  76
#define CELLS (WR*WC)      // 1368 float4 cells = 21.9 KB
#define NTHR 256
#define NK  ((CELLS + NTHR - 1)/NTHR)   // 6
#define NKH 3              // half of NK

__global__ __launch_bounds__(NTHR, 2)
void mdcn_kernel(const float* __restrict__ x,
                 const float* __restrict__ offset,
                 const float* __restrict__ mask,
                 const float* __restrict__ dynw,
                 float* __restrict__ out)
{
    __shared__ float4 lds[CELLS];

    const int blk = blockIdx.x;
    const int hs = blk & (NHS - 1);
    const int cg = (blk >> 4) & (NCG - 1);
    const int b  = blk >> 7;
    const int tid = threadIdx.x;
    const int w = tid & 63;
    const int h0 = hs * ROWS;
    const int h = h0 + (tid >> 6);

    const float* xg = x + (size_t)(b * CC + cg * CH) * HWs;

    // ---- split register staging: two halves of the window ----
    float4 stgA[NKH];   // k = 0..2, loaded before compute
    float4 stgB[NKH];   // k = 3..5, loaded after compute, pre-barrier

    #define LOAD_HALF(ARR, K0, XP)                                            \
    do {                                                                      \
        const float* xp_ = (XP);                                              \
        _Pragma("unroll")                                                     \
        for (int k = 0; k < NKH; ++k) {                                       \
            const int idx = tid + (k + (K0)) * NTHR;                          \
            float4 v = make_float4(0.f, 0.f, 0.f, 0.f);                       \
            if (idx < CELLS) {                                                \
                const int row = idx / WC;                                     \
                const int col = idx - row * WC - CLO;                         \
                const int ar  = h0 - WLO + row;                               \
                if ((unsigned)ar < (unsigned)HH &&                            \
                    (unsigned)col < (unsigned)WW) {                           \
                    const float* pp = xp_ + ar * WW + col;                    \
                    v.x = pp[0 * HWs]; v.y = pp[1 * HWs];                     \
                    v.z = pp[2 * HWs]; v.w = pp[3 * HWs];                     \
                }                                                             \
            }                                                                 \
            (ARR)[k] = v;                                                     \
        }                                                                     \
    } while (0)

    #define WRITE_HALF(ARR, K0)                                               \
    do {                                                                      \
        _Pragma("unroll")                                                     \
        for (int k = 0; k < NKH; ++k) {                                       \
            const int idx = tid + (k + (K0)) * NTHR;                          \
            if (idx < CELLS) lds[idx] = (ARR)[k];                             \
        }                                                                     \
    } while (0)

    // prologue: stage group 0 (both halves); metadata overlaps load latency
    LOAD_HALF(stgA, 0, xg);
    LOAD_HALF(stgB, NKH, xg);

    // ---- per-tap metadata: m, dy, dx + window offset (compact, 36 regs) ----
    float mv[KKT], dyv[KKT], dxv[KKT];
    int   woff[KKT];
    int   badmask = 0;
    const float* offp = offset + (size_t)b * (2 * KKT) * HWs + h * WW + w;
    const float* mskp = mask   + (size_t)b * KKT * HWs       + h * WW + w;
    #pragma unroll
    for (int t = 0; t < KKT; ++t) {
        const float oy = offp[(2 * t)     * HWs];
        const float ox = offp[(2 * t + 1) * HWs];
        const float m  = mskp[t * HWs];
        const float py = (float)(h - 1 + t / 3) + oy;
        const float px = (float)(w - 1 + t % 3) + ox;
        const float fy = floorf(py), fx = floorf(px);
        const int y0 = (int)fy, x0 = (int)fx;
        dyv[t] = py - fy;
        dxv[t] = px - fx;
        const bool inwin = (y0 >= h0 - WLO) && (y0 <= h0 - WLO + WR - 2) &&
                           (x0 >= -CLO)     && (x0 <= -CLO + WC - 2);
        if (!inwin) {
            badmask |= (1 << t);
            woff[t] = 0;
            mv[t] = 0.f;               // zeroes the LDS contribution
        } else {
            woff[t] = (y0 - (h0 - WLO)) * WC + (x0 + CLO);
            mv[t] = m;                 // pads hold zeros -> no corner masks
        }
    }
    const int anybad = __any(badmask != 0);

    WRITE_HALF(stgA, 0);
    WRITE_HALF(stgB, NKH);
    __syncthreads();

    const float* wtb  = dynw + (size_t)(b * CC + cg * CH) * KKT;
    float*       outp = out  + (size_t)(b * CC + cg * CH) * HWs + h * WW + w;

    for (int it = 0; it < NIT; ++it) {
        // H1 prefetch for next group: hidden under this group's compute
        if (it + 1 < NIT) {
            LOAD_HALF(stgA, 0, xg + (size_t)(it + 1) * CPI * HWs);
        }

        const float* wt = wtb + it * CPI * KKT;
        float s0 = 0.f, s1 = 0.f, s2 = 0.f, s3 = 0.f;

        #pragma unroll
        for (int t = 0; t < KKT; ++t) {
            const float4 c00 = lds[woff[t]];
            const float4 c01 = lds[woff[t] + 1];
            const float4 c10 = lds[woff[t] + WC];
            const float4 c11 = lds[woff[t] + WC + 1];
            const float dy = dyv[t], dx = dxv[t], m = mv[t];
            const float omdy = 1.f - dy, omdx = 1.f - dx;
            const float w00 = omdy * omdx * m, w01 = omdy * dx * m;
            const float w10 = dy * omdx * m,   w11 = dy * dx * m;
            const float v0 = c00.x * w00 + c01.x * w01 + c10.x * w10 + c11.x * w11;
            const float v1 = c00.y * w00 + c01.y * w01 + c10.y * w10 + c11.y * w11;
            const float v2 = c00.z * w00 + c01.z * w01 + c10.z * w10 + c11.z * w11;
            const float v3 = c00.w * w00 + c01.w * w01 + c10.w * w10 + c11.w * w11;
            s0 += v0 * wt[0 * KKT + t];
            s1 += v1 * wt[1 * KKT + t];
            s2 += v2 * wt[2 * KKT + t];
            s3 += v3 * wt[3 * KKT + t];
        }

        // rare corrective path for out-of-window taps (exact reference math)
        if (anybad) {
            #pragma unroll
            for (int t = 0; t < KKT; ++t) {
                if (badmask & (1 << t)) {
                    const float oy = offp[(2 * t)     * HWs];
                    const float ox = offp[(2 * t + 1) * HWs];
                    const float m  = mskp[t * HWs];
                    const float py = (float)(h - 1 + t / 3) + oy;
                    const float px = (float)(w - 1 + t % 3) + ox;
                    const float fy = floorf(py), fx = floorf(px);
                    const float dy = py - fy, dx = px - fx;
                    const int y0 = (int)fy, x0 = (int)fx;
                    const int y1 = y0 + 1,  x1 = x0 + 1;
                    const int cy0 = min(max(y0, 0), HH - 1);
                    const int cy1 = min(max(y1, 0), HH - 1);
                    const int cx0 = min(max(x0, 0), WW - 1);
                    const int cx1 = min(max(x1, 0), WW - 1);
                    const float m00 = ((unsigned)y0 < HH && (unsigned)x0 < WW) ? 1.f : 0.f;
                    const float m01 = ((unsigned)y0 < HH && (unsigned)x1 < WW) ? 1.f : 0.f;
                    const float m10 = ((unsigned)y1 < HH && (unsigned)x0 < WW) ? 1.f : 0.f;
                    const float m11 = ((unsigned)y1 < HH && (unsigned)x1 < WW) ? 1.f : 0.f;
                    const float omdy = 1.f - dy, omdx = 1.f - dx;
                    #pragma unroll
                    for (int c = 0; c < CPI; ++c) {
                        const float* pl = xg + (size_t)(it * CPI + c) * HWs;
                        const float v = pl[cy0 * WW + cx0] * m00 * (omdy * omdx)
                                      + pl[cy0 * WW + cx1] * m01 * (omdy * dx)
                                      + pl[cy1 * WW + cx0] * m10 * (dy * omdx)
                                      + pl[cy1 * WW + cx1] * m11 * (dy * dx);
                        const float add = v * m * wt[c * KKT + t];
                        if      (c == 0) s0 += add;
                        else if (c == 1) s1 += add;
                        else if (c == 2) s2 += add;
                        else             s3 += add;
                    }
                }
            }
        }

        // H2 loads for next group: issued now, latency hidden under the
        // output stores + barrier arrival skew
        if (it + 1 < NIT) {
            LOAD_HALF(stgB, NKH, xg + (size_t)(it + 1) * CPI * HWs);
        }

        outp[(size_t)(it * CPI + 0) * HWs] = s0;
        outp[(size_t)(it * CPI + 1) * HWs] = s1;
        outp[(size_t)(it * CPI + 2) * HWs] = s2;
        outp[(size_t)(it * CPI + 3) * HWs] = s3;

        if (it + 1 < NIT) {
            __syncthreads();   // all reads of current buffer done
            WRITE_HALF(stgA, 0);
            WRITE_HALF(stgB, NKH);
            __syncthreads();   // next buffer visible
        }
    }
    #undef LOAD_HALF
    #undef WRITE_HALF
}

extern "C" void kernel_launch(void* const* d_in, const int* in_sizes, int n_in,
                              void* d_out, int out_size, void* d_ws, size_t ws_size,
                              hipStream_t stream) {
    const float* x      = (const float*)d_in[0];
    const float* offset = (const float*)d_in[1];
    const float* mask   = (const float*)d_in[2];
    const float* dynw   = (const float*)d_in[3];
    float* out = (float*)d_out;

    dim3 grid(BB * NCG * NHS);   // 8 * 8 * 16 = 1024 blocks
    dim3 block(NTHR);
    mdcn_kernel<<<grid, block, 0, stream>>>(x, offset, mask, dynw, out);
}

// Round 11
// 36.584 us; speedup vs baseline: 2.3763x; 1.0677x over previous
//
#include <hip/hip_runtime.h>

// Modulated deformable depthwise conv, B=8 C=128 H=W=64 K=3 PAD=1 STRIDE=1.
// Round 10: attack the persistent spill (VGPR pinned at 128, ~48MB scratch
// in rounds 8/9) by lowering STATIC peak pressure, not by re-splitting:
//  (1) corrective path hoisted to the TOP of each iteration, before stg is
//      live -- its ~20 temps no longer stack on top of the staging regs
//      (it is execz-skipped at runtime: expected ~1.4 bad taps/dispatch);
//  (2) double-buffered LDS (2 x 21.9 KB, still 3 blocks/CU): ONE barrier
//      per iteration, ds_writes target the idle buffer;
//  (3) single stg[6] prefetch hidden under the tap loop (unchanged).

#define BB 8
#define CC 128
#define HH 64
#define WW 64
#define HWs (HH*WW)
#define KKT 9
#define CH 16              // channels per block
#define NCG (CC/CH)        // 8
#define CPI 4              // channels per LDS float4 cell
#define NIT (CH/CPI)       // 4
#define ROWS 4             // output rows per block
#define NHS (HH/ROWS)      // 16
#define WLO 6
#define WR  (ROWS+14)      // 18 staged rows
#define CLO 6
#define WC  76
#define CELLS (WR*WC)      // 1368 float4 cells = 21.9 KB per buffer
#define NTHR 256
#define NK  ((CELLS + NTHR - 1)/NTHR)   // 6

__global__ __launch_bounds__(NTHR, 2)
void mdcn_kernel(const float* __restrict__ x,
                 const float* __restrict__ offset,
                 const float* __restrict__ mask,
                 const float* __restrict__ dynw,
                 float* __restrict__ out)
{
    __shared__ float4 lds[2][CELLS];

    const int blk = blockIdx.x;
    const int hs = blk & (NHS - 1);
    const int cg = (blk >> 4) & (NCG - 1);
    const int b  = blk >> 7;
    const int tid = threadIdx.x;
    const int w = tid & 63;
    const int h0 = hs * ROWS;
    const int h = h0 + (tid >> 6);

    const float* xg = x + (size_t)(b * CC + cg * CH) * HWs;

    float4 stg[NK];
    #define STAGE_LOAD(XP)                                                    \
    do {                                                                      \
        const float* xp_ = (XP);                                              \
        _Pragma("unroll")                                                     \
        for (int k = 0; k < NK; ++k) {                                        \
            const int idx = tid + k * NTHR;                                   \
            float4 v = make_float4(0.f, 0.f, 0.f, 0.f);                       \
            if (idx < CELLS) {                                                \
                const int row = idx / WC;                                     \
                const int col = idx - row * WC - CLO;                         \
                const int ar  = h0 - WLO + row;                               \
                if ((unsigned)ar < (unsigned)HH &&                            \
                    (unsigned)col < (unsigned)WW) {                           \
                    const float* pp = xp_ + ar * WW + col;                    \
                    v.x = pp[0 * HWs]; v.y = pp[1 * HWs];                     \
                    v.z = pp[2 * HWs]; v.w = pp[3 * HWs];                     \
                }                                                             \
            }                                                                 \
            stg[k] = v;                                                       \
        }                                                                     \
    } while (0)

    #define STAGE_WRITE(DST)                                                  \
    do {                                                                      \
        float4* Lb_ = &lds[DST][0];                                           \
        _Pragma("unroll")                                                     \
        for (int k = 0; k < NK; ++k) {                                        \
            const int idx = tid + k * NTHR;                                   \
            if (idx < CELLS) Lb_[idx] = stg[k];                               \
        }                                                                     \
    } while (0)

    // prologue: stage group 0 into buf0; metadata overlaps load latency
    STAGE_LOAD(xg);

    // ---- per-tap metadata: m, dy, dx + window offset (compact) ----
    float mv[KKT], dyv[KKT], dxv[KKT];
    int   woff[KKT];
    int   badmask = 0;
    const float* offp = offset + (size_t)b * (2 * KKT) * HWs + h * WW + w;
    const float* mskp = mask   + (size_t)b * KKT * HWs       + h * WW + w;
    #pragma unroll
    for (int t = 0; t < KKT; ++t) {
        const float oy = offp[(2 * t)     * HWs];
        const float ox = offp[(2 * t + 1) * HWs];
        const float m  = mskp[t * HWs];
        const float py = (float)(h - 1 + t / 3) + oy;
        const float px = (float)(w - 1 + t % 3) + ox;
        const float fy = floorf(py), fx = floorf(px);
        const int y0 = (int)fy, x0 = (int)fx;
        dyv[t] = py - fy;
        dxv[t] = px - fx;
        const bool inwin = (y0 >= h0 - WLO) && (y0 <= h0 - WLO + WR - 2) &&
                           (x0 >= -CLO)     && (x0 <= -CLO + WC - 2);
        if (!inwin) {
            badmask |= (1 << t);
            woff[t] = 0;
            mv[t] = 0.f;               // zeroes the LDS contribution
        } else {
            woff[t] = (y0 - (h0 - WLO)) * WC + (x0 + CLO);
            mv[t] = m;                 // pads hold zeros -> no corner masks
        }
    }
    const int anybad = __any(badmask != 0);

    STAGE_WRITE(0);
    __syncthreads();

    const float* wtb  = dynw + (size_t)(b * CC + cg * CH) * KKT;
    float*       outp = out  + (size_t)(b * CC + cg * CH) * HWs + h * WW + w;

    for (int it = 0; it < NIT; ++it) {
        const float* wt = wtb + it * CPI * KKT;
        float s0 = 0.f, s1 = 0.f, s2 = 0.f, s3 = 0.f;

        // corrective path FIRST (stg not yet live; execz-skipped at runtime)
        if (anybad) {
            #pragma unroll
            for (int t = 0; t < KKT; ++t) {
                if (badmask & (1 << t)) {
                    const float oy = offp[(2 * t)     * HWs];
                    const float ox = offp[(2 * t + 1) * HWs];
                    const float m  = mskp[t * HWs];
                    const float py = (float)(h - 1 + t / 3) + oy;
                    const float px = (float)(w - 1 + t % 3) + ox;
                    const float fy = floorf(py), fx = floorf(px);
                    const float dy = py - fy, dx = px - fx;
                    const int y0 = (int)fy, x0 = (int)fx;
                    const int y1 = y0 + 1,  x1 = x0 + 1;
                    const int cy0 = min(max(y0, 0), HH - 1);
                    const int cy1 = min(max(y1, 0), HH - 1);
                    const int cx0 = min(max(x0, 0), WW - 1);
                    const int cx1 = min(max(x1, 0), WW - 1);
                    const float m00 = ((unsigned)y0 < HH && (unsigned)x0 < WW) ? 1.f : 0.f;
                    const float m01 = ((unsigned)y0 < HH && (unsigned)x1 < WW) ? 1.f : 0.f;
                    const float m10 = ((unsigned)y1 < HH && (unsigned)x0 < WW) ? 1.f : 0.f;
                    const float m11 = ((unsigned)y1 < HH && (unsigned)x1 < WW) ? 1.f : 0.f;
                    const float omdy = 1.f - dy, omdx = 1.f - dx;
                    #pragma unroll
                    for (int c = 0; c < CPI; ++c) {
                        const float* pl = xg + (size_t)(it * CPI + c) * HWs;
                        const float v = pl[cy0 * WW + cx0] * m00 * (omdy * omdx)
                                      + pl[cy0 * WW + cx1] * m01 * (omdy * dx)
                                      + pl[cy1 * WW + cx0] * m10 * (dy * omdx)
                                      + pl[cy1 * WW + cx1] * m11 * (dy * dx);
                        const float add = v * m * wt[c * KKT + t];
                        if      (c == 0) s0 += add;
                        else if (c == 1) s1 += add;
                        else if (c == 2) s2 += add;
                        else             s3 += add;
                    }
                }
            }
        }

        // prefetch next group (hidden under the tap loop)
        if (it + 1 < NIT) {
            STAGE_LOAD(xg + (size_t)(it + 1) * CPI * HWs);
        }

        const float4* Lp = &lds[it & 1][0];
        #pragma unroll
        for (int t = 0; t < KKT; ++t) {
            const float4 c00 = Lp[woff[t]];
            const float4 c01 = Lp[woff[t] + 1];
            const float4 c10 = Lp[woff[t] + WC];
            const float4 c11 = Lp[woff[t] + WC + 1];
            const float dy = dyv[t], dx = dxv[t], m = mv[t];
            const float omdy = 1.f - dy, omdx = 1.f - dx;
            const float w00 = omdy * omdx * m, w01 = omdy * dx * m;
            const float w10 = dy * omdx * m,   w11 = dy * dx * m;
            const float v0 = c00.x * w00 + c01.x * w01 + c10.x * w10 + c11.x * w11;
            const float v1 = c00.y * w00 + c01.y * w01 + c10.y * w10 + c11.y * w11;
            const float v2 = c00.z * w00 + c01.z * w01 + c10.z * w10 + c11.z * w11;
            const float v3 = c00.w * w00 + c01.w * w01 + c10.w * w10 + c11.w * w11;
            s0 += v0 * wt[0 * KKT + t];
            s1 += v1 * wt[1 * KKT + t];
            s2 += v2 * wt[2 * KKT + t];
            s3 += v3 * wt[3 * KKT + t];
        }

        // write next group into the IDLE buffer (no pre-barrier needed)
        if (it + 1 < NIT) {
            STAGE_WRITE((it + 1) & 1);
        }

        outp[(size_t)(it * CPI + 0) * HWs] = s0;
        outp[(size_t)(it * CPI + 1) * HWs] = s1;
        outp[(size_t)(it * CPI + 2) * HWs] = s2;
        outp[(size_t)(it * CPI + 3) * HWs] = s3;

        if (it + 1 < NIT) {
            __syncthreads();   // writes visible; old buffer free for reuse
        }
    }
    #undef STAGE_LOAD
    #undef STAGE_WRITE
}

extern "C" void kernel_launch(void* const* d_in, const int* in_sizes, int n_in,
                              void* d_out, int out_size, void* d_ws, size_t ws_size,
                              hipStream_t stream) {
    const float* x      = (const float*)d_in[0];
    const float* offset = (const float*)d_in[1];
    const float* mask   = (const float*)d_in[2];
    const float* dynw   = (const float*)d_in[3];
    float* out = (float*)d_out;

    dim3 grid(BB * NCG * NHS);   // 8 * 8 * 16 = 1024 blocks
    dim3 block(NTHR);
    mdcn_kernel<<<grid, block, 0, stream>>>(x, offset, mask, dynw, out);
}

// Round 12
// 35.657 us; speedup vs baseline: 2.4381x; 1.0260x over previous
//
#include <hip/hip_runtime.h>

// Modulated deformable depthwise conv, B=8 C=128 H=W=64 K=3 PAD=1 STRIDE=1.
// Round 11: single-buffer LDS (21.9 KB). Round 10's double buffer (44 KB)
// was LDS-capped at 3 blocks/CU; with grid 1024 = 4x256 that left a lone-
// block tail phase (measured occupancy 17%). Single buffer + VGPR 108 ->
// exactly 4 blocks/CU, one clean phase, 16 waves/CU. Cost: one extra
// barrier per iteration (read-drain before same-buffer overwrite).
// Keeps round 10's fixes: corrective path hoisted before stg is live
// (register-pressure relief; execz-skipped at runtime), stg[6] prefetch
// hidden under the tap loop, compact (m,dy,dx) metadata.

#define BB 8
#define CC 128
#define HH 64
#define WW 64
#define HWs (HH*WW)
#define KKT 9
#define CH 16              // channels per block
#define NCG (CC/CH)        // 8
#define CPI 4              // channels per LDS float4 cell
#define NIT (CH/CPI)       // 4
#define ROWS 4             // output rows per block
#define NHS (HH/ROWS)      // 16
#define WLO 6
#define WR  (ROWS+14)      // 18 staged rows
#define CLO 6
#define WC  76
#define CELLS (WR*WC)      // 1368 float4 cells = 21.9 KB
#define NTHR 256
#define NK  ((CELLS + NTHR - 1)/NTHR)   // 6

__global__ __launch_bounds__(NTHR, 2)
void mdcn_kernel(const float* __restrict__ x,
                 const float* __restrict__ offset,
                 const float* __restrict__ mask,
                 const float* __restrict__ dynw,
                 float* __restrict__ out)
{
    __shared__ float4 lds[CELLS];

    const int blk = blockIdx.x;
    const int hs = blk & (NHS - 1);
    const int cg = (blk >> 4) & (NCG - 1);
    const int b  = blk >> 7;
    const int tid = threadIdx.x;
    const int w = tid & 63;
    const int h0 = hs * ROWS;
    const int h = h0 + (tid >> 6);

    const float* xg = x + (size_t)(b * CC + cg * CH) * HWs;

    float4 stg[NK];
    #define STAGE_LOAD(XP)                                                    \
    do {                                                                      \
        const float* xp_ = (XP);                                              \
        _Pragma("unroll")                                                     \
        for (int k = 0; k < NK; ++k) {                                        \
            const int idx = tid + k * NTHR;                                   \
            float4 v = make_float4(0.f, 0.f, 0.f, 0.f);                       \
            if (idx < CELLS) {                                                \
                const int row = idx / WC;                                     \
                const int col = idx - row * WC - CLO;                         \
                const int ar  = h0 - WLO + row;                               \
                if ((unsigned)ar < (unsigned)HH &&                            \
                    (unsigned)col < (unsigned)WW) {                           \
                    const float* pp = xp_ + ar * WW + col;                    \
                    v.x = pp[0 * HWs]; v.y = pp[1 * HWs];                     \
                    v.z = pp[2 * HWs]; v.w = pp[3 * HWs];                     \
                }                                                             \
            }                                                                 \
            stg[k] = v;                                                       \
        }                                                                     \
    } while (0)

    #define STAGE_WRITE()                                                     \
    do {                                                                      \
        _Pragma("unroll")                                                     \
        for (int k = 0; k < NK; ++k) {                                        \
            const int idx = tid + k * NTHR;                                   \
            if (idx < CELLS) lds[idx] = stg[k];                               \
        }                                                                     \
    } while (0)

    // prologue: stage group 0; metadata VALU overlaps load latency
    STAGE_LOAD(xg);

    // ---- per-tap metadata: m, dy, dx + window offset (compact) ----
    float mv[KKT], dyv[KKT], dxv[KKT];
    int   woff[KKT];
    int   badmask = 0;
    const float* offp = offset + (size_t)b * (2 * KKT) * HWs + h * WW + w;
    const float* mskp = mask   + (size_t)b * KKT * HWs       + h * WW + w;
    #pragma unroll
    for (int t = 0; t < KKT; ++t) {
        const float oy = offp[(2 * t)     * HWs];
        const float ox = offp[(2 * t + 1) * HWs];
        const float m  = mskp[t * HWs];
        const float py = (float)(h - 1 + t / 3) + oy;
        const float px = (float)(w - 1 + t % 3) + ox;
        const float fy = floorf(py), fx = floorf(px);
        const int y0 = (int)fy, x0 = (int)fx;
        dyv[t] = py - fy;
        dxv[t] = px - fx;
        const bool inwin = (y0 >= h0 - WLO) && (y0 <= h0 - WLO + WR - 2) &&
                           (x0 >= -CLO)     && (x0 <= -CLO + WC - 2);
        if (!inwin) {
            badmask |= (1 << t);
            woff[t] = 0;
            mv[t] = 0.f;               // zeroes the LDS contribution
        } else {
            woff[t] = (y0 - (h0 - WLO)) * WC + (x0 + CLO);
            mv[t] = m;                 // pads hold zeros -> no corner masks
        }
    }
    const int anybad = __any(badmask != 0);

    STAGE_WRITE();
    __syncthreads();

    const float* wtb  = dynw + (size_t)(b * CC + cg * CH) * KKT;
    float*       outp = out  + (size_t)(b * CC + cg * CH) * HWs + h * WW + w;

    for (int it = 0; it < NIT; ++it) {
        const float* wt = wtb + it * CPI * KKT;
        float s0 = 0.f, s1 = 0.f, s2 = 0.f, s3 = 0.f;

        // corrective path FIRST (stg not yet live; execz-skipped at runtime)
        if (anybad) {
            #pragma unroll
            for (int t = 0; t < KKT; ++t) {
                if (badmask & (1 << t)) {
                    const float oy = offp[(2 * t)     * HWs];
                    const float ox = offp[(2 * t + 1) * HWs];
                    const float m  = mskp[t * HWs];
                    const float py = (float)(h - 1 + t / 3) + oy;
                    const float px = (float)(w - 1 + t % 3) + ox;
                    const float fy = floorf(py), fx = floorf(px);
                    const float dy = py - fy, dx = px - fx;
                    const int y0 = (int)fy, x0 = (int)fx;
                    const int y1 = y0 + 1,  x1 = x0 + 1;
                    const int cy0 = min(max(y0, 0), HH - 1);
                    const int cy1 = min(max(y1, 0), HH - 1);
                    const int cx0 = min(max(x0, 0), WW - 1);
                    const int cx1 = min(max(x1, 0), WW - 1);
                    const float m00 = ((unsigned)y0 < HH && (unsigned)x0 < WW) ? 1.f : 0.f;
                    const float m01 = ((unsigned)y0 < HH && (unsigned)x1 < WW) ? 1.f : 0.f;
                    const float m10 = ((unsigned)y1 < HH && (unsigned)x0 < WW) ? 1.f : 0.f;
                    const float m11 = ((unsigned)y1 < HH && (unsigned)x1 < WW) ? 1.f : 0.f;
                    const float omdy = 1.f - dy, omdx = 1.f - dx;
                    #pragma unroll
                    for (int c = 0; c < CPI; ++c) {
                        const float* pl = xg + (size_t)(it * CPI + c) * HWs;
                        const float v = pl[cy0 * WW + cx0] * m00 * (omdy * omdx)
                                      + pl[cy0 * WW + cx1] * m01 * (omdy * dx)
                                      + pl[cy1 * WW + cx0] * m10 * (dy * omdx)
                                      + pl[cy1 * WW + cx1] * m11 * (dy * dx);
                        const float add = v * m * wt[c * KKT + t];
                        if      (c == 0) s0 += add;
                        else if (c == 1) s1 += add;
                        else if (c == 2) s2 += add;
                        else             s3 += add;
                    }
                }
            }
        }

        // prefetch next group (hidden under the tap loop)
        if (it + 1 < NIT) {
            STAGE_LOAD(xg + (size_t)(it + 1) * CPI * HWs);
        }

        #pragma unroll
        for (int t = 0; t < KKT; ++t) {
            const float4 c00 = lds[woff[t]];
            const float4 c01 = lds[woff[t] + 1];
            const float4 c10 = lds[woff[t] + WC];
            const float4 c11 = lds[woff[t] + WC + 1];
            const float dy = dyv[t], dx = dxv[t], m = mv[t];
            const float omdy = 1.f - dy, omdx = 1.f - dx;
            const float w00 = omdy * omdx * m, w01 = omdy * dx * m;
            const float w10 = dy * omdx * m,   w11 = dy * dx * m;
            const float v0 = c00.x * w00 + c01.x * w01 + c10.x * w10 + c11.x * w11;
            const float v1 = c00.y * w00 + c01.y * w01 + c10.y * w10 + c11.y * w11;
            const float v2 = c00.z * w00 + c01.z * w01 + c10.z * w10 + c11.z * w11;
            const float v3 = c00.w * w00 + c01.w * w01 + c10.w * w10 + c11.w * w11;
            s0 += v0 * wt[0 * KKT + t];
            s1 += v1 * wt[1 * KKT + t];
            s2 += v2 * wt[2 * KKT + t];
            s3 += v3 * wt[3 * KKT + t];
        }

        outp[(size_t)(it * CPI + 0) * HWs] = s0;
        outp[(size_t)(it * CPI + 1) * HWs] = s1;
        outp[(size_t)(it * CPI + 2) * HWs] = s2;
        outp[(size_t)(it * CPI + 3) * HWs] = s3;

        if (it + 1 < NIT) {
            __syncthreads();   // all reads of the buffer done
            STAGE_WRITE();     // overwrite with prefetched next group
            __syncthreads();   // writes visible
        }
    }
    #undef STAGE_LOAD
    #undef STAGE_WRITE
}

extern "C" void kernel_launch(void* const* d_in, const int* in_sizes, int n_in,
                              void* d_out, int out_size, void* d_ws, size_t ws_size,
                              hipStream_t stream) {
    const float* x      = (const float*)d_in[0];
    const float* offset = (const float*)d_in[1];
    const float* mask   = (const float*)d_in[2];
    const float* dynw   = (const float*)d_in[3];
    float* out = (float*)d_out;

    dim3 grid(BB * NCG * NHS);   // 8 * 8 * 16 = 1024 blocks
    dim3 block(NTHR);
    mdcn_kernel<<<grid, block, 0, stream>>>(x, offset, mask, dynw, out);
}